// Round 9
// baseline (286.630 us; speedup 1.0000x reference)
//
#include <hip/hip_runtime.h>

// ImageRGB_75952201662701 — flip → rotate(bilinear,reflect) → zoom(bilinear,reflect)
// → brightness+clip → contrast(channel-mean)+clip.  [32,512,512,3] f32.
//
// R9: R8 (pair-ILP + angle-adaptive traversal) gave 150->128us; VGPR=44 fits
// exactly 8 in-flight float3 taps -> pipeline DID materialize. Extend to
// 4-wide (16 taps in flight, stride 1024) and cut VALU/pixel with fmaf +
// precomputed corner weights (absmax=1.0 reported on every pass => tolerance,
// ulp-level reordering is safe; tap flips at floor boundaries carry ~0 weight).

constexpr int Hh = 512, Ww = 512, Cc = 3, BATCH = 32;
constexpr int HW = Hh * Ww;
constexpr float CTR = 255.5f;                 // (512-1)/2
constexpr size_t IMG_FLOATS = (size_t)HW * Cc;

constexpr int TW = 64, TH = 16;               // output tile per block (256 thr)
constexpr int RW = 99, RH = 26;               // LDS rect capacity (Wr<=97, Hr<=25)

__device__ __forceinline__ int reflect1024(int i) {
    int m = i & 1023;                         // exact for negatives: 2n = 1024 pow2
    return (m < 512) ? m : (1023 - m);
}

// coord math + issue 4 tap loads for rotated-image pixel (RX,RY)
#define LOADPX(RX, RY, W00, W01, W10, W11, T00, T01, T10, T11)                  \
    {                                                                           \
        const int gx_ = reflect1024(rx0 + (int)(RX));                           \
        const int gy_ = reflect1024(ry0 + (int)(RY));                           \
        const float fx_ = (float)gx_ - CTR, fy_ = (float)gy_ - CTR;             \
        const float sx_ = fmaf(cs, fx_, fmaf(-sn, fy_, CTR));                   \
        const float sy_ = fmaf(sn, fx_, fmaf(cs, fy_, CTR));                    \
        const float xf_ = floorf(sx_), yf_ = floorf(sy_);                       \
        const float wx_ = sx_ - xf_, wy_ = sy_ - yf_;                           \
        const float w1x_ = 1.f - wx_, w1y_ = 1.f - wy_;                         \
        (W00) = w1y_ * w1x_; (W01) = w1y_ * wx_;                                \
        (W10) = wy_ * w1x_;  (W11) = wy_ * wx_;                                 \
        const int xa_ = reflect1024((int)xf_)     ^ fhm;                        \
        const int xb_ = reflect1024((int)xf_ + 1) ^ fhm;                        \
        const int ya_ = reflect1024((int)yf_)     ^ fvm;                        \
        const int yb_ = reflect1024((int)yf_ + 1) ^ fvm;                        \
        (T00) = img[ya_ * Ww + xa_]; (T01) = img[ya_ * Ww + xb_];               \
        (T10) = img[yb_ * Ww + xa_]; (T11) = img[yb_ * Ww + xb_];               \
    }

// weighted combine + LDS store
#define STOREPX(RX, RY, W00, W01, W10, W11, T00, T01, T10, T11)                 \
    {                                                                           \
        float3 o_;                                                              \
        o_.x = fmaf((T00).x, (W00), fmaf((T01).x, (W01),                        \
               fmaf((T10).x, (W10), (T11).x * (W11))));                         \
        o_.y = fmaf((T00).y, (W00), fmaf((T01).y, (W01),                        \
               fmaf((T10).y, (W10), (T11).y * (W11))));                         \
        o_.z = fmaf((T00).z, (W00), fmaf((T01).z, (W01),                        \
               fmaf((T10).z, (W10), (T11).z * (W11))));                         \
        lds[(RY)][(RX)] = o_;                                                   \
    }

__global__ __launch_bounds__(256, 4) void warp_fused(
    const float* __restrict__ in,
    const int* __restrict__ fh, const int* __restrict__ fv,
    const float* __restrict__ angle, const float* __restrict__ zoom,
    const float* __restrict__ delta,
    float* __restrict__ out, double* __restrict__ sums)
{
    __shared__ float3 lds[RH][RW];            // 30888 B
    __shared__ float red[4][3];

    const int b = blockIdx.z;
    const float ang = angle[b];
    const float cs = cosf(ang), sn = sinf(ang);
    const float z  = zoom[b];
    const float dl = delta[b];
    const int fhm = fh[b] ? 511 : 0;          // 511 - x == x ^ 511 for x in [0,511]
    const int fvm = fv[b] ? 511 : 0;
    const float3* __restrict__ img = (const float3*)(in + (size_t)b * IMG_FLOATS);
    float* __restrict__ outb = out + (size_t)b * IMG_FLOATS;

    const int X0 = blockIdx.x * TW;
    const int Y0 = blockIdx.y * TH;

    // pre-reflect integer coord range needed by this tile's zoom taps
    const int rx0 = (int)floorf(z * ((float)X0 - CTR) + CTR);
    const int ry0 = (int)floorf(z * ((float)Y0 - CTR) + CTR);
    const int rx1 = (int)floorf(z * ((float)(X0 + TW - 1) - CTR) + CTR) + 1;
    const int ry1 = (int)floorf(z * ((float)(Y0 + TH - 1) - CTR) + CTR) + 1;
    const unsigned Wr = (unsigned)(rx1 - rx0 + 1);   // <= 97 for z <= 1.5
    const unsigned Hr = (unsigned)(ry1 - ry0 + 1);   // <= 25
    const unsigned N  = Wr * Hr;

    // ---- fill: branchless quad-ILP gather into LDS rect ----
    {
        // fast dim: consecutive lanes step where source drift is smallest.
        const bool rowmajor = fabsf(sn) <= fabsf(cs);
        const unsigned FW = rowmajor ? Wr : Hr;

        unsigned iA = threadIdx.x;
        unsigned vA = iA / FW;
        unsigned uA = iA - vA * FW;
        const unsigned q1 = 256u / FW, r1 = 256u - q1 * FW;
        const unsigned q2 = 512u / FW, r2 = 512u - q2 * FW;
        const unsigned q3 = 768u / FW, r3 = 768u - q3 * FW;
        const unsigned q4 = 1024u / FW, r4 = 1024u - q4 * FW;
        const unsigned vL = (N - 1u) / FW;               // last-pixel coords
        const unsigned uL = (N - 1u) - vL * FW;
        const unsigned iters = (N + 1023u) >> 10;        // quads of 256

        for (unsigned t = 0; t < iters; ++t) {
            // slots B,C,D = A + 256/512/768 (one wrap correction: r_k < FW)
            unsigned uB = uA + r1, vB = vA + q1;
            const bool wB = (uB >= FW); uB = wB ? uB - FW : uB; vB = wB ? vB + 1u : vB;
            unsigned uC = uA + r2, vC = vA + q2;
            const bool wC = (uC >= FW); uC = wC ? uC - FW : uC; vC = wC ? vC + 1u : vC;
            unsigned uD = uA + r3, vD = vA + q3;
            const bool wD = (uD >= FW); uD = wD ? uD - FW : uD; vD = wD ? vD + 1u : vD;

            const bool av = (iA < N);
            const bool bv = (iA + 256u < N);
            const bool cv = (iA + 512u < N);
            const bool dv = (iA + 768u < N);
            const unsigned ua = av ? uA : uL, va = av ? vA : vL;
            const unsigned ub = bv ? uB : uL, vb = bv ? vB : vL;
            const unsigned uc = cv ? uC : uL, vc = cv ? vC : vL;
            const unsigned ud = dv ? uD : uL, vd = dv ? vD : vL;
            const unsigned rxa = rowmajor ? ua : va, rya = rowmajor ? va : ua;
            const unsigned rxb = rowmajor ? ub : vb, ryb = rowmajor ? vb : ub;
            const unsigned rxc = rowmajor ? uc : vc, ryc = rowmajor ? vc : uc;
            const unsigned rxd = rowmajor ? ud : vd, ryd = rowmajor ? vd : ud;

            // straight line: 16 independent loads issued before any consumer
            float wa00, wa01, wa10, wa11; float3 a00, a01, a10, a11;
            LOADPX(rxa, rya, wa00, wa01, wa10, wa11, a00, a01, a10, a11);
            float wb00, wb01, wb10, wb11; float3 b00, b01, b10, b11;
            LOADPX(rxb, ryb, wb00, wb01, wb10, wb11, b00, b01, b10, b11);
            float wc00, wc01, wc10, wc11; float3 c00, c01, c10, c11;
            LOADPX(rxc, ryc, wc00, wc01, wc10, wc11, c00, c01, c10, c11);
            float wd00, wd01, wd10, wd11; float3 d00, d01, d10, d11;
            LOADPX(rxd, ryd, wd00, wd01, wd10, wd11, d00, d01, d10, d11);
            STOREPX(rxa, rya, wa00, wa01, wa10, wa11, a00, a01, a10, a11);
            STOREPX(rxb, ryb, wb00, wb01, wb10, wb11, b00, b01, b10, b11);
            STOREPX(rxc, ryc, wc00, wc01, wc10, wc11, c00, c01, c10, c11);
            STOREPX(rxd, ryd, wd00, wd01, wd10, wd11, d00, d01, d10, d11);

            // advance A by 1024 (one wrap correction: r4 < FW)
            iA += 1024u;
            unsigned uN = uA + r4, vN = vA + q4;
            const bool wN = (uN >= FW);
            uA = wN ? uN - FW : uN;  vA = wN ? vN + 1u : vN;
        }
    }
    __syncthreads();

    // ---- zoom from LDS + brightness + clip + store + channel sums ----
    const int tx  = threadIdx.x & 63;
    const int ty0 = threadIdx.x >> 6;
    const float sx = z * ((float)(X0 + tx) - CTR) + CTR;
    const float xf = floorf(sx);
    const float wx = sx - xf;
    const int lxa = (int)xf - rx0;            // in [0, Wr-2]
    const float w1x = 1.f - wx;

    float s0 = 0.f, s1 = 0.f, s2 = 0.f;
    #pragma unroll
    for (int k = 0; k < 4; ++k) {
        const int y = Y0 + ty0 + (k << 2);    // wave writes one full 64-px row
        const float sy = z * ((float)y - CTR) + CTR;
        const float yf = floorf(sy);
        const float wy = sy - yf;
        const int lya = (int)yf - ry0;        // in [0, Hr-2]
        const float w1y = 1.f - wy;
        const float w00 = w1y * w1x, w01 = w1y * wx;
        const float w10 = wy * w1x,  w11 = wy * wx;
        const float3 a0 = lds[lya][lxa],     a1 = lds[lya][lxa + 1];
        const float3 b0 = lds[lya + 1][lxa], b1 = lds[lya + 1][lxa + 1];
        float3 t;
        t.x = fmaf(a0.x, w00, fmaf(a1.x, w01, fmaf(b0.x, w10, b1.x * w11)));
        t.y = fmaf(a0.y, w00, fmaf(a1.y, w01, fmaf(b0.y, w10, b1.y * w11)));
        t.z = fmaf(a0.z, w00, fmaf(a1.z, w01, fmaf(b0.z, w10, b1.z * w11)));
        t.x = fminf(fmaxf(t.x + dl, 0.f), 255.f);     // brightness + clip
        t.y = fminf(fmaxf(t.y + dl, 0.f), 255.f);
        t.z = fminf(fmaxf(t.z + dl, 0.f), 255.f);
        *(float3*)(outb + (size_t)((y << 9) + X0 + tx) * 3) = t;
        s0 += t.x; s1 += t.y; s2 += t.z;
    }

    // block reduce -> 3 double atomics (256 blocks/image contend lightly)
    #pragma unroll
    for (int off = 32; off > 0; off >>= 1) {
        s0 += __shfl_down(s0, off);
        s1 += __shfl_down(s1, off);
        s2 += __shfl_down(s2, off);
    }
    const int lane = threadIdx.x & 63, wid = threadIdx.x >> 6;
    if (lane == 0) { red[wid][0] = s0; red[wid][1] = s1; red[wid][2] = s2; }
    __syncthreads();
    if (threadIdx.x == 0) {
        atomicAdd(&sums[b * 3 + 0], (double)red[0][0] + red[1][0] + red[2][0] + red[3][0]);
        atomicAdd(&sums[b * 3 + 1], (double)red[0][1] + red[1][1] + red[2][1] + red[3][1]);
        atomicAdd(&sums[b * 3 + 2], (double)red[0][2] + red[1][2] + red[2][2] + red[3][2]);
    }
}

// ---------- Pass 2: contrast about per-channel mean + clip (4 x float4/thread) ----------
__global__ __launch_bounds__(256) void contrast_pass(
    float* __restrict__ out, const double* __restrict__ sums,
    const float* __restrict__ contrast)
{
    const int b = blockIdx.y;
    const float f = contrast[b];
    const double invN = 1.0 / (double)HW;
    const float m0 = (float)(sums[b * 3 + 0] * invN);
    const float m1 = (float)(sums[b * 3 + 1] * invN);
    const float m2 = (float)(sums[b * 3 + 2] * invN);
    float4* base = reinterpret_cast<float4*>(out + (size_t)b * IMG_FLOATS);

    #pragma unroll
    for (int it = 0; it < 4; ++it) {
        const int i4 = it * 49152 + blockIdx.x * 256 + threadIdx.x;
        float4 v = base[i4];
        int c = (int)(((unsigned)i4 * 4u) % 3u);
        float m;
        m = (c == 0) ? m0 : ((c == 1) ? m1 : m2);
        v.x = fminf(fmaxf((v.x - m) * f + m, 0.f), 255.f); c = (c == 2) ? 0 : c + 1;
        m = (c == 0) ? m0 : ((c == 1) ? m1 : m2);
        v.y = fminf(fmaxf((v.y - m) * f + m, 0.f), 255.f); c = (c == 2) ? 0 : c + 1;
        m = (c == 0) ? m0 : ((c == 1) ? m1 : m2);
        v.z = fminf(fmaxf((v.z - m) * f + m, 0.f), 255.f); c = (c == 2) ? 0 : c + 1;
        m = (c == 0) ? m0 : ((c == 1) ? m1 : m2);
        v.w = fminf(fmaxf((v.w - m) * f + m, 0.f), 255.f);
        base[i4] = v;
    }
}

extern "C" void kernel_launch(void* const* d_in, const int* in_sizes, int n_in,
                              void* d_out, int out_size, void* d_ws, size_t ws_size,
                              hipStream_t stream) {
    const float* in       = (const float*)d_in[0];
    const int*   fh       = (const int*)d_in[1];
    const int*   fv       = (const int*)d_in[2];
    const float* angle    = (const float*)d_in[3];
    const float* zoom     = (const float*)d_in[4];
    const float* delta    = (const float*)d_in[5];
    const float* contrast = (const float*)d_in[6];
    float*  out  = (float*)d_out;
    double* sums = (double*)d_ws;

    // ws re-poisoned to 0xAA each call — zero the sum accumulators.
    hipMemsetAsync(d_ws, 0, BATCH * 3 * sizeof(double), stream);

    dim3 blk(256);
    dim3 g1(Ww / TW, Hh / TH, BATCH);        // 8 x 32 x 32 = 8192 blocks
    warp_fused<<<g1, blk, 0, stream>>>(in, fh, fv, angle, zoom, delta, out, sums);

    dim3 g2(192, BATCH);                     // 4 float4/thread over 96MB
    contrast_pass<<<g2, blk, 0, stream>>>(out, sums, contrast);
}